// Round 6
// baseline (658.632 us; speedup 1.0000x reference)
//
#include <hip/hip_runtime.h>

#define NN 512          // nodes
#define IND 512         // in features
#define NH 8            // heads
#define NF 64           // hidden per head
#define NBLK 1024

// ---------------------------------------------------------------------------
// Device-scope spin barrier, poison-robust (flags compared signed >= k;
// 0xAAAAAAAA poison and 0 both read "not arrived"). Iteration-capped so a
// broken co-residency assumption degrades to wrong-answer, never a hang.
// ---------------------------------------------------------------------------
__device__ __forceinline__ void gbar(int* flags, int k) {
    __syncthreads();   // block's stage work complete (drains stores to L2)
    if (threadIdx.x == 0) {
        // agent-scope release: prior global writes visible device-wide
        __hip_atomic_store(&flags[blockIdx.x], k,
                           __ATOMIC_RELEASE, __HIP_MEMORY_SCOPE_AGENT);
    }
    #pragma unroll 1
    for (int b = threadIdx.x; b < NBLK; b += 256) {
        int iters = 0;
        while (__hip_atomic_load(&flags[b],
                                 __ATOMIC_ACQUIRE, __HIP_MEMORY_SCOPE_AGENT) < k) {
            if (++iters > 2000000) break;        // safety valve
            __builtin_amdgcn_s_sleep(2);
        }
    }
    __threadfence();   // agent acquire fence: invalidate stale cached lines
    __syncthreads();
}

// ---------------------------------------------------------------------------
// Single fused kernel, 1024 blocks x 256 threads, 4 blocks/CU co-resident.
//   A0 (blocks 0..511): transpose X -> Xt, W_target -> Wtg_t
//   A1 (all): Gs_t[o][n] = Ws @ Xt ; Gt[n][o] = X @ Wtg_t
//             (uniform s_load row operand x coalesced col operand,
//              8 rows x 64 cols, 4-way wave split-K, LDS reduce)
//   B  (all): per (i-tile of 4, head): scores -> softmax -> att + out_feat
// ---------------------------------------------------------------------------
__global__ __launch_bounds__(256, 4) void gat_fused(
    const float* __restrict__ X,
    const float* __restrict__ Ws,
    const float* __restrict__ Wtg,
    const float* __restrict__ attn_w,
    const int*   __restrict__ adj,
    float* __restrict__ Xt,
    float* __restrict__ Wtg_t,
    float* __restrict__ Gs_t,      // [512 (h*64+f)][512 j]
    float* __restrict__ Gt,        // [512 n][512 (h*64+f)]
    int*   __restrict__ flags,     // [1024]
    float* __restrict__ out_feat,  // [512][512]
    float* __restrict__ out_att)   // [512][512][8]
{
    __shared__ __align__(16) char smem[12288];   // union of stage buffers
    float (*tile)[33]    = (float(*)[33])smem;            // A0: 4224 B
    float (*sp)[8][64]   = (float(*)[8][64])smem;         // A1: 8192 B
    float (*s_sc)[512]   = (float(*)[512])smem;           // B:  8192 B
    float (*s_red)[4][64]= (float(*)[4][64])(smem + 8192);// B:  4096 B

    const int tid = threadIdx.x;
    const int blk = blockIdx.x;

    // ---- Stage A0: transposes (512 active blocks, 32x32 tiles) ----
    if (blk < 512) {
        const float* src = (blk < 256) ? X : Wtg;
        float* dst       = (blk < 256) ? Xt : Wtg_t;
        const int t  = blk & 255;
        const int bx = (t & 15) << 5, by = (t >> 4) << 5;
        const int tx = tid & 31, r0 = (tid >> 5) << 2;
        #pragma unroll
        for (int r = 0; r < 4; ++r)
            tile[r0 + r][tx] = src[(size_t)(by + r0 + r) * NN + bx + tx];
        __syncthreads();
        #pragma unroll
        for (int r = 0; r < 4; ++r)
            dst[(size_t)(bx + r0 + r) * NN + by + tx] = tile[tx][r0 + r];
    }
    gbar(flags, 1);

    // ---- Stage A1: both GEMMs ----
    {
        const int mat = blk >> 9;            // 0: Gs_t, 1: Gt
        const int b   = blk & 511;
        const int r0  = (b >> 3) << 3;       // 64 row-groups of 8
        const int c0  = (b & 7) << 6;        // 8 col-groups of 64
        const float* S = mat ? X : Ws;       // uniform row operand
        const float* V = mat ? Wtg_t : Xt;   // coalesced col operand
        float*       C = mat ? Gt : Gs_t;
        const int kh   = __builtin_amdgcn_readfirstlane(tid >> 6);
        const int lane = tid & 63;
        const float* Sp = S + (size_t)r0 * IND + kh * 128;
        const float* Vp = V + (size_t)(kh * 128) * NN + c0 + lane;

        float acc[8] = {0.f, 0.f, 0.f, 0.f, 0.f, 0.f, 0.f, 0.f};
        #pragma unroll 4
        for (int k = 0; k < 128; ++k) {
            float v = Vp[(size_t)k * NN];
            #pragma unroll
            for (int r = 0; r < 8; ++r)
                acc[r] = fmaf(Sp[(size_t)r * IND + k], v, acc[r]);
        }
        #pragma unroll
        for (int r = 0; r < 8; ++r) sp[kh][r][lane] = acc[r];
        __syncthreads();
        #pragma unroll
        for (int q = 0; q < 2; ++q) {
            const int o = tid + q * 256;
            const int r = o >> 6, c = o & 63;
            C[(size_t)(r0 + r) * NN + c0 + c] =
                sp[0][r][c] + sp[1][r][c] + sp[2][r][c] + sp[3][r][c];
        }
    }
    gbar(flags, 2);

    // ---- Stage B: attention ----
    const int i0 = (blk >> 3) << 2;
    const int h  = blk & 7;

    // phase 1: scores; w*lrelu(t) = 0.6w*t + 0.4w*|t|
    {
        const int jj = tid * 2;
        float2 a0 = {0.f,0.f}, a1 = {0.f,0.f}, a2 = {0.f,0.f}, a3 = {0.f,0.f};
        const float* gsp = Gs_t + (size_t)h * NF * NN + jj;
        const float* gtp = Gt + (size_t)i0 * IND + h * NF;
        #pragma unroll 4
        for (int f = 0; f < NF; ++f) {
            float w  = attn_w[f];            // uniform -> s_load
            float w6 = 0.6f * w, w4 = 0.4f * w;
            float2 g = *reinterpret_cast<const float2*>(gsp + (size_t)f * NN);
            float gt0 = gtp[f];              // uniform -> s_load
            float gt1 = gtp[IND + f];
            float gt2 = gtp[2 * IND + f];
            float gt3 = gtp[3 * IND + f];
            float tx, ty;
            tx = g.x + gt0; ty = g.y + gt0;
            a0.x = fmaf(w4, fabsf(tx), fmaf(w6, tx, a0.x));
            a0.y = fmaf(w4, fabsf(ty), fmaf(w6, ty, a0.y));
            tx = g.x + gt1; ty = g.y + gt1;
            a1.x = fmaf(w4, fabsf(tx), fmaf(w6, tx, a1.x));
            a1.y = fmaf(w4, fabsf(ty), fmaf(w6, ty, a1.y));
            tx = g.x + gt2; ty = g.y + gt2;
            a2.x = fmaf(w4, fabsf(tx), fmaf(w6, tx, a2.x));
            a2.y = fmaf(w4, fabsf(ty), fmaf(w6, ty, a2.y));
            tx = g.x + gt3; ty = g.y + gt3;
            a3.x = fmaf(w4, fabsf(tx), fmaf(w6, tx, a3.x));
            a3.y = fmaf(w4, fabsf(ty), fmaf(w6, ty, a3.y));
        }
        int2 ad;
        ad = *reinterpret_cast<const int2*>(adj + (size_t)(i0 + 0) * NN + jj);
        s_sc[0][jj]     = ad.x ? a0.x : -INFINITY;
        s_sc[0][jj + 1] = ad.y ? a0.y : -INFINITY;
        ad = *reinterpret_cast<const int2*>(adj + (size_t)(i0 + 1) * NN + jj);
        s_sc[1][jj]     = ad.x ? a1.x : -INFINITY;
        s_sc[1][jj + 1] = ad.y ? a1.y : -INFINITY;
        ad = *reinterpret_cast<const int2*>(adj + (size_t)(i0 + 2) * NN + jj);
        s_sc[2][jj]     = ad.x ? a2.x : -INFINITY;
        s_sc[2][jj + 1] = ad.y ? a2.y : -INFINITY;
        ad = *reinterpret_cast<const int2*>(adj + (size_t)(i0 + 3) * NN + jj);
        s_sc[3][jj]     = ad.x ? a3.x : -INFINITY;
        s_sc[3][jj + 1] = ad.y ? a3.y : -INFINITY;
    }
    __syncthreads();

    // phase 2: softmax over j (scores bounded -> no max pass; exp(-inf)=0)
    {
        const int ii = tid >> 6, lane = tid & 63;
        float e[8];
        float sum = 0.f;
        #pragma unroll
        for (int r = 0; r < 8; ++r) {
            float ev = __expf(s_sc[ii][lane + r * 64]);
            e[r] = ev;
            sum += ev;
        }
        #pragma unroll
        for (int off = 32; off >= 1; off >>= 1) sum += __shfl_xor(sum, off, 64);
        float inv = 1.f / sum;
        const int i = i0 + ii;
        #pragma unroll
        for (int r = 0; r < 8; ++r) {
            const int j = lane + r * 64;
            float a = e[r] * inv;
            s_sc[ii][j] = a;
            out_att[((size_t)i * NN + j) * NH + h] = a;
        }
    }
    __syncthreads();

    // phase 3: head_output = att @ Gt (waves split j; coalesced Gt reads)
    {
        const int w = tid >> 6, lane = tid & 63;
        const int jb = w * 128;
        float o0 = 0.f, o1 = 0.f, o2 = 0.f, o3 = 0.f;
        const float* gtc = Gt + h * NF + lane;
        #pragma unroll 4
        for (int s = 0; s < 32; ++s) {
            const int j = jb + 4 * s;
            float4 b0 = *reinterpret_cast<const float4*>(&s_sc[0][j]);
            float4 b1 = *reinterpret_cast<const float4*>(&s_sc[1][j]);
            float4 b2 = *reinterpret_cast<const float4*>(&s_sc[2][j]);
            float4 b3 = *reinterpret_cast<const float4*>(&s_sc[3][j]);
            float gv;
            gv = gtc[(size_t)(j + 0) * IND];
            o0 = fmaf(b0.x, gv, o0); o1 = fmaf(b1.x, gv, o1);
            o2 = fmaf(b2.x, gv, o2); o3 = fmaf(b3.x, gv, o3);
            gv = gtc[(size_t)(j + 1) * IND];
            o0 = fmaf(b0.y, gv, o0); o1 = fmaf(b1.y, gv, o1);
            o2 = fmaf(b2.y, gv, o2); o3 = fmaf(b3.y, gv, o3);
            gv = gtc[(size_t)(j + 2) * IND];
            o0 = fmaf(b0.z, gv, o0); o1 = fmaf(b1.z, gv, o1);
            o2 = fmaf(b2.z, gv, o2); o3 = fmaf(b3.z, gv, o3);
            gv = gtc[(size_t)(j + 3) * IND];
            o0 = fmaf(b0.w, gv, o0); o1 = fmaf(b1.w, gv, o1);
            o2 = fmaf(b2.w, gv, o2); o3 = fmaf(b3.w, gv, o3);
        }
        s_red[w][0][lane] = o0; s_red[w][1][lane] = o1;
        s_red[w][2][lane] = o2; s_red[w][3][lane] = o3;
    }
    __syncthreads();
    {
        const int ii = tid >> 6, f = tid & 63;
        float s = s_red[0][ii][f] + s_red[1][ii][f] + s_red[2][ii][f] + s_red[3][ii][f];
        out_feat[(size_t)(i0 + ii) * (NH * NF) + h * NF + f] = s;
    }
}

extern "C" void kernel_launch(void* const* d_in, const int* in_sizes, int n_in,
                              void* d_out, int out_size, void* d_ws, size_t ws_size,
                              hipStream_t stream) {
    const float* X   = (const float*)d_in[0];   // h [1,512,512]
    const float* Ws  = (const float*)d_in[1];   // W_source [512,512]
    const float* Wtg = (const float*)d_in[2];   // W_target [512,512]
    const float* aw  = (const float*)d_in[3];   // attn_w [64]
    const int*   adj = (const int*)d_in[4];     // adjacency [512,512,1]

    float* Xt    = (float*)d_ws;                  // [512 k][512 n]
    float* Wtg_t = Xt    + (size_t)NN * IND;      // [512 k][512 o]
    float* Gs_t  = Wtg_t + (size_t)NN * IND;      // [512 o][512 n]
    float* Gt    = Gs_t  + (size_t)NN * IND;      // [512 n][512 o]
    int*   flags = (int*)(Gt + (size_t)NN * IND); // [1024]

    float* out_feat = (float*)d_out;                    // [512,512]
    float* out_att  = out_feat + (size_t)NN * NH * NF;  // [512,512,8]

    hipLaunchKernelGGL(gat_fused, dim3(NBLK), dim3(256), 0, stream,
                       X, Ws, Wtg, aw, adj, Xt, Wtg_t, Gs_t, Gt, flags,
                       out_feat, out_att);
}

// Round 7
// 476.432 us; speedup vs baseline: 1.3824x; 1.3824x over previous
//
#include <hip/hip_runtime.h>

#define NN 512          // nodes
#define IND 512         // in features
#define NH 8            // heads
#define NF 64           // hidden per head
#define NBLK 1024

// ---------------------------------------------------------------------------
// Two-phase centralized grid barrier. ONE atomicAdd + ONE poller per block
// (thread 0); everyone else parks at __syncthreads. cnt/gen zeroed by a
// hipMemsetAsync before launch (so 0xAA ws-poison can't corrupt them).
// gen is a write-once line -> pollers read a stable line from the LLC.
// Iteration-capped: a broken assumption gives wrong answer, never a hang.
// ---------------------------------------------------------------------------
__device__ __forceinline__ void gbar(int* cnt, int* gen) {
    __syncthreads();   // block's stage work complete
    if (threadIdx.x == 0) {
        int prev = __hip_atomic_fetch_add(cnt, 1, __ATOMIC_ACQ_REL,
                                          __HIP_MEMORY_SCOPE_AGENT);
        if (prev == NBLK - 1) {
            __hip_atomic_store(gen, 1, __ATOMIC_RELEASE,
                               __HIP_MEMORY_SCOPE_AGENT);
        } else {
            int iters = 0;
            while (__hip_atomic_load(gen, __ATOMIC_ACQUIRE,
                                     __HIP_MEMORY_SCOPE_AGENT) == 0) {
                if (++iters > 1000000) break;    // safety valve
                __builtin_amdgcn_s_sleep(2);
            }
        }
    }
    __syncthreads();   // release the other waves
    __threadfence();   // per-wave cache maintenance: fresh cross-XCD reads
}

// ---------------------------------------------------------------------------
// Single fused kernel, 1024 blocks x 256 threads, 4 blocks/CU co-resident.
//   A0 (blocks 0..511): transpose X -> Xt, W_target -> Wtg_t
//   A1 (all): Gs_t[o][n] = Ws @ Xt ; Gt[n][o] = X @ Wtg_t
//             (uniform s_load row operand x coalesced col operand,
//              8 rows x 64 cols, 4-way wave split-K, LDS reduce)
//   B  (all): per (i-tile of 4, head): scores -> softmax -> att + out_feat
// ---------------------------------------------------------------------------
__global__ __launch_bounds__(256, 4) void gat_fused(
    const float* __restrict__ X,
    const float* __restrict__ Ws,
    const float* __restrict__ Wtg,
    const float* __restrict__ attn_w,
    const int*   __restrict__ adj,
    float* __restrict__ Xt,
    float* __restrict__ Wtg_t,
    float* __restrict__ Gs_t,      // [512 (h*64+f)][512 j]
    float* __restrict__ Gt,        // [512 n][512 (h*64+f)]
    int*   __restrict__ bar,       // [64] ints: cnt0@0, gen0@16, cnt1@32, gen1@48
    float* __restrict__ out_feat,  // [512][512]
    float* __restrict__ out_att)   // [512][512][8]
{
    __shared__ __align__(16) char smem[12288];   // union of stage buffers
    float (*tile)[33]    = (float(*)[33])smem;            // A0: 4224 B
    float (*sp)[8][64]   = (float(*)[8][64])smem;         // A1: 8192 B
    float (*s_sc)[512]   = (float(*)[512])smem;           // B:  8192 B
    float (*s_red)[4][64]= (float(*)[4][64])(smem + 8192);// B:  4096 B

    const int tid = threadIdx.x;
    const int blk = blockIdx.x;

    // ---- Stage A0: transposes (512 active blocks, 32x32 tiles) ----
    if (blk < 512) {
        const float* src = (blk < 256) ? X : Wtg;
        float* dst       = (blk < 256) ? Xt : Wtg_t;
        const int t  = blk & 255;
        const int bx = (t & 15) << 5, by = (t >> 4) << 5;
        const int tx = tid & 31, r0 = (tid >> 5) << 2;
        #pragma unroll
        for (int r = 0; r < 4; ++r)
            tile[r0 + r][tx] = src[(size_t)(by + r0 + r) * NN + bx + tx];
        __syncthreads();
        #pragma unroll
        for (int r = 0; r < 4; ++r)
            dst[(size_t)(bx + r0 + r) * NN + by + tx] = tile[tx][r0 + r];
    }
    gbar(bar + 0, bar + 16);

    // ---- Stage A1: both GEMMs ----
    {
        const int mat = blk >> 9;            // 0: Gs_t, 1: Gt
        const int b   = blk & 511;
        const int r0  = (b >> 3) << 3;       // 64 row-groups of 8
        const int c0  = (b & 7) << 6;        // 8 col-groups of 64
        const float* S = mat ? X : Ws;       // uniform row operand
        const float* V = mat ? Wtg_t : Xt;   // coalesced col operand
        float*       C = mat ? Gt : Gs_t;
        const int kh   = __builtin_amdgcn_readfirstlane(tid >> 6);
        const int lane = tid & 63;
        const float* Sp = S + (size_t)r0 * IND + kh * 128;
        const float* Vp = V + (size_t)(kh * 128) * NN + c0 + lane;

        float acc[8] = {0.f, 0.f, 0.f, 0.f, 0.f, 0.f, 0.f, 0.f};
        #pragma unroll 4
        for (int k = 0; k < 128; ++k) {
            float v = Vp[(size_t)k * NN];
            #pragma unroll
            for (int r = 0; r < 8; ++r)
                acc[r] = fmaf(Sp[(size_t)r * IND + k], v, acc[r]);
        }
        #pragma unroll
        for (int r = 0; r < 8; ++r) sp[kh][r][lane] = acc[r];
        __syncthreads();
        #pragma unroll
        for (int q = 0; q < 2; ++q) {
            const int o = tid + q * 256;
            const int r = o >> 6, c = o & 63;
            C[(size_t)(r0 + r) * NN + c0 + c] =
                sp[0][r][c] + sp[1][r][c] + sp[2][r][c] + sp[3][r][c];
        }
    }
    gbar(bar + 32, bar + 48);

    // ---- Stage B: attention ----
    const int i0 = (blk >> 3) << 2;
    const int h  = blk & 7;

    // phase 1: scores; w*lrelu(t) = 0.6w*t + 0.4w*|t|
    {
        const int jj = tid * 2;
        float2 a0 = {0.f,0.f}, a1 = {0.f,0.f}, a2 = {0.f,0.f}, a3 = {0.f,0.f};
        const float* gsp = Gs_t + (size_t)h * NF * NN + jj;
        const float* gtp = Gt + (size_t)i0 * IND + h * NF;
        #pragma unroll 4
        for (int f = 0; f < NF; ++f) {
            float w  = attn_w[f];            // uniform -> s_load
            float w6 = 0.6f * w, w4 = 0.4f * w;
            float2 g = *reinterpret_cast<const float2*>(gsp + (size_t)f * NN);
            float gt0 = gtp[f];              // uniform -> s_load
            float gt1 = gtp[IND + f];
            float gt2 = gtp[2 * IND + f];
            float gt3 = gtp[3 * IND + f];
            float tx, ty;
            tx = g.x + gt0; ty = g.y + gt0;
            a0.x = fmaf(w4, fabsf(tx), fmaf(w6, tx, a0.x));
            a0.y = fmaf(w4, fabsf(ty), fmaf(w6, ty, a0.y));
            tx = g.x + gt1; ty = g.y + gt1;
            a1.x = fmaf(w4, fabsf(tx), fmaf(w6, tx, a1.x));
            a1.y = fmaf(w4, fabsf(ty), fmaf(w6, ty, a1.y));
            tx = g.x + gt2; ty = g.y + gt2;
            a2.x = fmaf(w4, fabsf(tx), fmaf(w6, tx, a2.x));
            a2.y = fmaf(w4, fabsf(ty), fmaf(w6, ty, a2.y));
            tx = g.x + gt3; ty = g.y + gt3;
            a3.x = fmaf(w4, fabsf(tx), fmaf(w6, tx, a3.x));
            a3.y = fmaf(w4, fabsf(ty), fmaf(w6, ty, a3.y));
        }
        int2 ad;
        ad = *reinterpret_cast<const int2*>(adj + (size_t)(i0 + 0) * NN + jj);
        s_sc[0][jj]     = ad.x ? a0.x : -INFINITY;
        s_sc[0][jj + 1] = ad.y ? a0.y : -INFINITY;
        ad = *reinterpret_cast<const int2*>(adj + (size_t)(i0 + 1) * NN + jj);
        s_sc[1][jj]     = ad.x ? a1.x : -INFINITY;
        s_sc[1][jj + 1] = ad.y ? a1.y : -INFINITY;
        ad = *reinterpret_cast<const int2*>(adj + (size_t)(i0 + 2) * NN + jj);
        s_sc[2][jj]     = ad.x ? a2.x : -INFINITY;
        s_sc[2][jj + 1] = ad.y ? a2.y : -INFINITY;
        ad = *reinterpret_cast<const int2*>(adj + (size_t)(i0 + 3) * NN + jj);
        s_sc[3][jj]     = ad.x ? a3.x : -INFINITY;
        s_sc[3][jj + 1] = ad.y ? a3.y : -INFINITY;
    }
    __syncthreads();

    // phase 2: softmax over j (scores bounded -> no max pass; exp(-inf)=0)
    {
        const int ii = tid >> 6, lane = tid & 63;
        float e[8];
        float sum = 0.f;
        #pragma unroll
        for (int r = 0; r < 8; ++r) {
            float ev = __expf(s_sc[ii][lane + r * 64]);
            e[r] = ev;
            sum += ev;
        }
        #pragma unroll
        for (int off = 32; off >= 1; off >>= 1) sum += __shfl_xor(sum, off, 64);
        float inv = 1.f / sum;
        const int i = i0 + ii;
        #pragma unroll
        for (int r = 0; r < 8; ++r) {
            const int j = lane + r * 64;
            float a = e[r] * inv;
            s_sc[ii][j] = a;
            out_att[((size_t)i * NN + j) * NH + h] = a;
        }
    }
    __syncthreads();

    // phase 3: head_output = att @ Gt (waves split j; coalesced Gt reads)
    {
        const int w = tid >> 6, lane = tid & 63;
        const int jb = w * 128;
        float o0 = 0.f, o1 = 0.f, o2 = 0.f, o3 = 0.f;
        const float* gtc = Gt + h * NF + lane;
        #pragma unroll 4
        for (int s = 0; s < 32; ++s) {
            const int j = jb + 4 * s;
            float4 b0 = *reinterpret_cast<const float4*>(&s_sc[0][j]);
            float4 b1 = *reinterpret_cast<const float4*>(&s_sc[1][j]);
            float4 b2 = *reinterpret_cast<const float4*>(&s_sc[2][j]);
            float4 b3 = *reinterpret_cast<const float4*>(&s_sc[3][j]);
            float gv;
            gv = gtc[(size_t)(j + 0) * IND];
            o0 = fmaf(b0.x, gv, o0); o1 = fmaf(b1.x, gv, o1);
            o2 = fmaf(b2.x, gv, o2); o3 = fmaf(b3.x, gv, o3);
            gv = gtc[(size_t)(j + 1) * IND];
            o0 = fmaf(b0.y, gv, o0); o1 = fmaf(b1.y, gv, o1);
            o2 = fmaf(b2.y, gv, o2); o3 = fmaf(b3.y, gv, o3);
            gv = gtc[(size_t)(j + 2) * IND];
            o0 = fmaf(b0.z, gv, o0); o1 = fmaf(b1.z, gv, o1);
            o2 = fmaf(b2.z, gv, o2); o3 = fmaf(b3.z, gv, o3);
            gv = gtc[(size_t)(j + 3) * IND];
            o0 = fmaf(b0.w, gv, o0); o1 = fmaf(b1.w, gv, o1);
            o2 = fmaf(b2.w, gv, o2); o3 = fmaf(b3.w, gv, o3);
        }
        s_red[w][0][lane] = o0; s_red[w][1][lane] = o1;
        s_red[w][2][lane] = o2; s_red[w][3][lane] = o3;
    }
    __syncthreads();
    {
        const int ii = tid >> 6, f = tid & 63;
        float s = s_red[0][ii][f] + s_red[1][ii][f] + s_red[2][ii][f] + s_red[3][ii][f];
        out_feat[(size_t)(i0 + ii) * (NH * NF) + h * NF + f] = s;
    }
}

extern "C" void kernel_launch(void* const* d_in, const int* in_sizes, int n_in,
                              void* d_out, int out_size, void* d_ws, size_t ws_size,
                              hipStream_t stream) {
    const float* X   = (const float*)d_in[0];   // h [1,512,512]
    const float* Ws  = (const float*)d_in[1];   // W_source [512,512]
    const float* Wtg = (const float*)d_in[2];   // W_target [512,512]
    const float* aw  = (const float*)d_in[3];   // attn_w [64]
    const int*   adj = (const int*)d_in[4];     // adjacency [512,512,1]

    float* Xt    = (float*)d_ws;                  // [512 k][512 n]
    float* Wtg_t = Xt    + (size_t)NN * IND;      // [512 k][512 o]
    float* Gs_t  = Wtg_t + (size_t)NN * IND;      // [512 o][512 n]
    float* Gt    = Gs_t  + (size_t)NN * IND;      // [512 n][512 o]
    int*   bar   = (int*)(Gt + (size_t)NN * IND); // [64] ints

    float* out_feat = (float*)d_out;                    // [512,512]
    float* out_att  = out_feat + (size_t)NN * NH * NF;  // [512,512,8]

    hipMemsetAsync(bar, 0, 64 * sizeof(int), stream);   // zero barrier state
    hipLaunchKernelGGL(gat_fused, dim3(NBLK), dim3(256), 0, stream,
                       X, Ws, Wtg, aw, adj, Xt, Wtg_t, Gs_t, Gt, bar,
                       out_feat, out_att);
}

// Round 8
// 119.303 us; speedup vs baseline: 5.5207x; 3.9935x over previous
//
#include <hip/hip_runtime.h>

#define NN 512          // nodes
#define IND 512         // in features
#define NH 8            // heads
#define NF 64           // hidden per head

// ---------------------------------------------------------------------------
// K1: build both projections as NT-GEMM with on-the-fly X transpose in LDS.
//   C[o][n] = sum_k S[o][k] * X[n][k]
//   z=0: S=W_source -> Gs_t[o][n];  z=1: S=W_target -> Gt_t[o][n]
// Block: 16 rows (o) x 64 cols (n); 4 waves x 4 rows; k-tiles of 64 staged
// into Xs[k][n] (transposed write, 2-way bank alias = free per m136).
// Inner loop/lane: 1 ds_read_b32 + 4 FMA -> VALU-bound.
// S reads are wave-uniform -> s_load through K$.
// Grid 512 blocks = 2 blocks/CU.
// ---------------------------------------------------------------------------
__global__ __launch_bounds__(256) void build_g(
    const float* __restrict__ X,
    const float* __restrict__ Ws,
    const float* __restrict__ Wtg,
    float* __restrict__ Gs_t,
    float* __restrict__ Gt_t)
{
    __shared__ float Xs[64][65];   // 16.6 KB, padded
    const int z = blockIdx.z;
    const float* S = z ? Wtg : Ws;
    float*       C = z ? Gt_t : Gs_t;
    const int c0 = blockIdx.x * 64;     // node-column group
    const int r0 = blockIdx.y * 16;     // output-row group
    const int tid  = threadIdx.x;
    const int wv   = __builtin_amdgcn_readfirstlane(tid >> 6);
    const int lane = tid & 63;
    const int crow = tid >> 2;          // 0..63: X row this thread stages
    const int kseg = (tid & 3) * 16;    // k-subrange within tile

    const float* xrow = X + (size_t)(c0 + crow) * IND;
    const float* srow = S + (size_t)(r0 + wv * 4) * IND;   // uniform

    float acc0 = 0.f, acc1 = 0.f, acc2 = 0.f, acc3 = 0.f;
    for (int kt = 0; kt < IND; kt += 64) {
        __syncthreads();
        #pragma unroll
        for (int q = 0; q < 4; ++q) {
            float4 xv = *reinterpret_cast<const float4*>(xrow + kt + kseg + 4 * q);
            Xs[kseg + 4 * q + 0][crow] = xv.x;
            Xs[kseg + 4 * q + 1][crow] = xv.y;
            Xs[kseg + 4 * q + 2][crow] = xv.z;
            Xs[kseg + 4 * q + 3][crow] = xv.w;
        }
        __syncthreads();
        #pragma unroll 8
        for (int k = 0; k < 64; ++k) {
            float v  = Xs[k][lane];
            float s0 = srow[kt + k];             // uniform -> s_load
            float s1 = srow[IND + kt + k];
            float s2 = srow[2 * IND + kt + k];
            float s3 = srow[3 * IND + kt + k];
            acc0 = fmaf(s0, v, acc0);
            acc1 = fmaf(s1, v, acc1);
            acc2 = fmaf(s2, v, acc2);
            acc3 = fmaf(s3, v, acc3);
        }
    }
    float* cp = C + (size_t)(r0 + wv * 4) * NN + c0 + lane;
    cp[0]          = acc0;
    cp[NN]         = acc1;
    cp[2 * NN]     = acc2;
    cp[3 * NN]     = acc3;
}

// ---------------------------------------------------------------------------
// K2: per (i-tile of 4, head h) block.
//   phase 1: scores: Gs_t coalesced over j; Gt_t via ONE uniform
//            s_load_dwordx4 per f (covers ii=0..3); w*lrelu folded:
//            w*lrelu(t) = 0.6w*t + 0.4w*|t|
//   phase 2: softmax over j (bounded scores -> no max pass); direct
//            out_att[i][j][h] write (R5 proved staging+transpose is a loss).
//   phase 3: head_out = att @ g_target read from Gt_t: one float4 PER LANE
//            per 4 j (contiguous per-lane row stream, L1-resident).
// ---------------------------------------------------------------------------
__global__ __launch_bounds__(256) void gat_attn(
    const float* __restrict__ Gs_t,      // [512 (h*64+f)][512 j]
    const float* __restrict__ Gt_t,      // [512 (h*64+f)][512 n]
    const float* __restrict__ attn_w,    // [64]
    const int*   __restrict__ adj,       // [512][512]
    float* __restrict__ out_feat,        // [512][512]
    float* __restrict__ out_att)         // [512][512][8]
{
    __shared__ float s_sc[4][512];
    __shared__ float s_red[4][4][64];

    const int tid = threadIdx.x;
    const int i0  = blockIdx.x * 4;
    const int h   = blockIdx.y;

    // ---- phase 1: scores (2 j's per thread) ----
    {
        const int jj = tid * 2;
        float2 a0 = {0.f,0.f}, a1 = {0.f,0.f}, a2 = {0.f,0.f}, a3 = {0.f,0.f};
        const float* gsp = Gs_t + (size_t)h * NF * NN + jj;
        const float4* gtq = reinterpret_cast<const float4*>(
                                Gt_t + (size_t)h * NF * NN) + (i0 >> 2);
        #pragma unroll 4
        for (int f = 0; f < NF; ++f) {
            float w  = attn_w[f];             // uniform -> s_load
            float w6 = 0.6f * w, w4 = 0.4f * w;
            float2 g = *reinterpret_cast<const float2*>(gsp + (size_t)f * NN);
            float4 gt = gtq[(size_t)f * (NN / 4)];   // uniform s_load_dwordx4
            float tx, ty;
            tx = g.x + gt.x; ty = g.y + gt.x;
            a0.x = fmaf(w4, fabsf(tx), fmaf(w6, tx, a0.x));
            a0.y = fmaf(w4, fabsf(ty), fmaf(w6, ty, a0.y));
            tx = g.x + gt.y; ty = g.y + gt.y;
            a1.x = fmaf(w4, fabsf(tx), fmaf(w6, tx, a1.x));
            a1.y = fmaf(w4, fabsf(ty), fmaf(w6, ty, a1.y));
            tx = g.x + gt.z; ty = g.y + gt.z;
            a2.x = fmaf(w4, fabsf(tx), fmaf(w6, tx, a2.x));
            a2.y = fmaf(w4, fabsf(ty), fmaf(w6, ty, a2.y));
            tx = g.x + gt.w; ty = g.y + gt.w;
            a3.x = fmaf(w4, fabsf(tx), fmaf(w6, tx, a3.x));
            a3.y = fmaf(w4, fabsf(ty), fmaf(w6, ty, a3.y));
        }
        int2 ad;
        ad = *reinterpret_cast<const int2*>(adj + (size_t)(i0 + 0) * NN + jj);
        s_sc[0][jj]     = ad.x ? a0.x : -INFINITY;
        s_sc[0][jj + 1] = ad.y ? a0.y : -INFINITY;
        ad = *reinterpret_cast<const int2*>(adj + (size_t)(i0 + 1) * NN + jj);
        s_sc[1][jj]     = ad.x ? a1.x : -INFINITY;
        s_sc[1][jj + 1] = ad.y ? a1.y : -INFINITY;
        ad = *reinterpret_cast<const int2*>(adj + (size_t)(i0 + 2) * NN + jj);
        s_sc[2][jj]     = ad.x ? a2.x : -INFINITY;
        s_sc[2][jj + 1] = ad.y ? a2.y : -INFINITY;
        ad = *reinterpret_cast<const int2*>(adj + (size_t)(i0 + 3) * NN + jj);
        s_sc[3][jj]     = ad.x ? a3.x : -INFINITY;
        s_sc[3][jj + 1] = ad.y ? a3.y : -INFINITY;
    }
    __syncthreads();

    // ---- phase 2: softmax over j; direct attention write ----
    {
        const int ii = tid >> 6, lane = tid & 63;
        float e[8];
        float sum = 0.f;
        #pragma unroll
        for (int r = 0; r < 8; ++r) {
            float ev = __expf(s_sc[ii][lane + r * 64]);
            e[r] = ev;
            sum += ev;
        }
        #pragma unroll
        for (int off = 32; off >= 1; off >>= 1) sum += __shfl_xor(sum, off, 64);
        float inv = 1.f / sum;
        const int i = i0 + ii;
        #pragma unroll
        for (int r = 0; r < 8; ++r) {
            const int j = lane + r * 64;
            float a = e[r] * inv;
            s_sc[ii][j] = a;
            out_att[((size_t)i * NN + j) * NH + h] = a;
        }
    }
    __syncthreads();

    // ---- phase 3: head_out = att @ Gt_t rows (waves split j) ----
    {
        const int w = tid >> 6, lane = tid & 63;
        const int jb = w * 128;
        float o0 = 0.f, o1 = 0.f, o2 = 0.f, o3 = 0.f;
        const float* gtr = Gt_t + (size_t)(h * NF + lane) * NN;  // own row
        #pragma unroll 4
        for (int s = 0; s < 32; ++s) {
            const int j = jb + 4 * s;
            float4 gv = *reinterpret_cast<const float4*>(gtr + j);
            float4 b0 = *reinterpret_cast<const float4*>(&s_sc[0][j]);
            float4 b1 = *reinterpret_cast<const float4*>(&s_sc[1][j]);
            float4 b2 = *reinterpret_cast<const float4*>(&s_sc[2][j]);
            float4 b3 = *reinterpret_cast<const float4*>(&s_sc[3][j]);
            o0 = fmaf(b0.x, gv.x, fmaf(b0.y, gv.y, fmaf(b0.z, gv.z, fmaf(b0.w, gv.w, o0))));
            o1 = fmaf(b1.x, gv.x, fmaf(b1.y, gv.y, fmaf(b1.z, gv.z, fmaf(b1.w, gv.w, o1))));
            o2 = fmaf(b2.x, gv.x, fmaf(b2.y, gv.y, fmaf(b2.z, gv.z, fmaf(b2.w, gv.w, o2))));
            o3 = fmaf(b3.x, gv.x, fmaf(b3.y, gv.y, fmaf(b3.z, gv.z, fmaf(b3.w, gv.w, o3))));
        }
        s_red[w][0][lane] = o0; s_red[w][1][lane] = o1;
        s_red[w][2][lane] = o2; s_red[w][3][lane] = o3;
    }
    __syncthreads();
    {
        const int ii = tid >> 6, f = tid & 63;
        float s = s_red[0][ii][f] + s_red[1][ii][f] + s_red[2][ii][f] + s_red[3][ii][f];
        out_feat[(size_t)(i0 + ii) * (NH * NF) + h * NF + f] = s;
    }
}

extern "C" void kernel_launch(void* const* d_in, const int* in_sizes, int n_in,
                              void* d_out, int out_size, void* d_ws, size_t ws_size,
                              hipStream_t stream) {
    const float* X   = (const float*)d_in[0];   // h [1,512,512]
    const float* Ws  = (const float*)d_in[1];   // W_source [512,512]
    const float* Wtg = (const float*)d_in[2];   // W_target [512,512]
    const float* aw  = (const float*)d_in[3];   // attn_w [64]
    const int*   adj = (const int*)d_in[4];     // adjacency [512,512,1]

    float* Gs_t = (float*)d_ws;                 // [512 o][512 n]
    float* Gt_t = Gs_t + (size_t)NN * IND;      // [512 o][512 n]

    float* out_feat = (float*)d_out;                    // [512,512]
    float* out_att  = out_feat + (size_t)NN * NH * NF;  // [512,512,8]

    hipLaunchKernelGGL(build_g, dim3(8, 32, 2), dim3(256), 0, stream,
                       X, Ws, Wtg, Gs_t, Gt_t);
    hipLaunchKernelGGL(gat_attn, dim3(NN / 4, NH), dim3(256), 0, stream,
                       Gs_t, Gt_t, aw, adj, out_feat, out_att);
}